// Round 1
// baseline (337.194 us; speedup 1.0000x reference)
//
#include <hip/hip_runtime.h>
#include <stdint.h>

// DCN-V2 MoE low-rank cross network, fused both layers, bf16 MFMA.
// B=16384 D=1024 R=64 E=4 L=2.
//
// Per layer (per 32-row block):
//   GEMM1: Y[32,272] = x_l[32,1024] @ W1  (W1 = [V cols e*64+r | gateW^T | pad])
//   gate  = softmax over 4 logit cols (every wave computes the gate N-tile)
//   v     = tanh(Y[:,0:256]);  per-wave expert slice in LDS
//   c     = tanh(v @ C[e]^T);  gc = gate_e * c   -> LDS [32][256] bf16
//   GEMM2: Z[32,1024] = gc @ W2  (W2[k=e*64+r][d] = U[e,d,r])
//   out   = x0 .* (Z + bias) + x_l    (residual; layer0 result re-staged as bf16 x_l)
//
// Weights pre-packed into MFMA B-fragment order (prep kernel) in d_ws:
//   frag(kt,nt): 64 lanes x 8 bf16, value = W[kt*32+(lane>>4)*8+j][nt*16+(lane&15)]

typedef __attribute__((ext_vector_type(8))) short bf16x8;
typedef __attribute__((ext_vector_type(4))) float f32x4;

#define MFMA_BF16(a, b, c) __builtin_amdgcn_mfma_f32_16x16x32_bf16((a), (b), (c), 0, 0, 0)

static constexpr int kB = 16384, kD = 1024;
static constexpr int MTILE = 32;

// workspace layout in ushort elems
static constexpr size_t W1F_OFF = 0;                         // [L][32 kt][17 nt][64][8]
static constexpr size_t W1F_SZ  = 2ull * 32 * 17 * 64 * 8;   // 557056
static constexpr size_t W2F_OFF = W1F_OFF + W1F_SZ;          // [L][8 kt][64 nt][64][8]
static constexpr size_t W2F_SZ  = 2ull * 8 * 64 * 64 * 8;    // 524288
static constexpr size_t CF_OFF  = W2F_OFF + W2F_SZ;          // [L][E][2 kt][4 nt][64][8]

__device__ __forceinline__ unsigned short f2bf(float f) {
    uint32_t u = __builtin_bit_cast(uint32_t, f);
    u = (u + 0x7FFFu + ((u >> 16) & 1u)) >> 16;   // RNE
    return (unsigned short)u;
}
__device__ __forceinline__ float bf2f(unsigned short h) {
    uint32_t u = ((uint32_t)h) << 16;
    return __builtin_bit_cast(float, u);
}
__device__ __forceinline__ float fast_tanh(float x) {
    // tanh(x) = 1 - 2/(exp2(2*log2e*x)+1); correct +/-1 saturation via inf/0
    float e = __builtin_amdgcn_exp2f(x * 2.8853900817779268f);
    return 1.0f - 2.0f * __builtin_amdgcn_rcpf(e + 1.0f);
}
__device__ __forceinline__ float fast_exp(float x) {
    return __builtin_amdgcn_exp2f(x * 1.4426950408889634f);
}

// ---------------- weight prep: fp32 -> bf16 MFMA B-fragments ----------------
__global__ __launch_bounds__(256) void prep_weights(
    const float* __restrict__ U, const float* __restrict__ V,
    const float* __restrict__ C, const float* __restrict__ gateW,
    unsigned short* __restrict__ ws)
{
    const int id = blockIdx.x * 256 + threadIdx.x;
    const int lane = id & 63;
    const int kg = lane >> 4, c = lane & 15;
    if (id < 2 * 32 * 17 * 64) {                       // W1 fragments
        int t = id >> 6;
        int nt = t % 17; t /= 17;
        int kt = t & 31; int i = t >> 5;
        int col = nt * 16 + c;
        bf16x8 o;
#pragma unroll
        for (int j = 0; j < 8; ++j) {
            int k = kt * 32 + kg * 8 + j;              // k = d
            float v = 0.0f;
            if (col < 256) {
                int e = col >> 6, r = col & 63;
                v = V[((size_t)(i * 4 + e) * 1024 + k) * 64 + r];
            } else if (col < 260) {
                v = gateW[(size_t)(col - 256) * 1024 + k];
            }
            o[j] = (short)f2bf(v);
        }
        *(bf16x8*)(ws + W1F_OFF + (size_t)id * 8) = o;
    } else if (id < 2 * 32 * 17 * 64 + 2 * 8 * 64 * 64) {  // W2 fragments
        int id2 = id - 2 * 32 * 17 * 64;
        int t = id2 >> 6;
        int nt = t & 63; t >>= 6;
        int kt = t & 7;  int i = t >> 3;
        int d = nt * 16 + c;
        bf16x8 o;
#pragma unroll
        for (int j = 0; j < 8; ++j) {
            int k = kt * 32 + kg * 8 + j;              // k = e*64 + r
            int e = k >> 6, r = k & 63;
            o[j] = (short)f2bf(U[((size_t)(i * 4 + e) * 1024 + d) * 64 + r]);
        }
        *(bf16x8*)(ws + W2F_OFF + (size_t)id2 * 8) = o;
    } else if (id < 2 * 32 * 17 * 64 + 2 * 8 * 64 * 64 + 2 * 4 * 2 * 4 * 64) {  // C frags
        int id3 = id - (2 * 32 * 17 * 64 + 2 * 8 * 64 * 64);
        int t = id3 >> 6;
        int nt = t & 3; t >>= 2;
        int kt = t & 1; t >>= 1;
        int e = t & 3;  int i = t >> 2;
        int r = nt * 16 + c;
        bf16x8 o;
#pragma unroll
        for (int j = 0; j < 8; ++j) {
            int q = kt * 32 + kg * 8 + j;
            o[j] = (short)f2bf(C[((size_t)(i * 4 + e) * 64 + r) * 64 + q]);
        }
        *(bf16x8*)(ws + CF_OFF + (size_t)id3 * 8) = o;
    }
}

// ---------------- fused main kernel ----------------
__global__ __launch_bounds__(256) void dcn_main(
    const float* __restrict__ x, const float* __restrict__ bias,
    const unsigned short* __restrict__ ws, float* __restrict__ out)
{
    __shared__ char smem[64 * 1024 + 16 * 1024];   // 80 KiB -> 2 blocks/CU
    char* xl = smem;                    // x_l tile [32][1024] bf16, XOR-swizzled
    char* sh = smem + 64 * 1024;        // 16 KiB: v slices (4KB/wave), then gc [32][256]

    const unsigned short* w1f = ws + W1F_OFF;
    const unsigned short* w2f = ws + W2F_OFF;
    const unsigned short* cf  = ws + CF_OFF;

    const int tid = threadIdx.x;
    const int lane = tid & 63, wid = tid >> 6;
    const int kg = lane >> 4, lc = lane & 15;
    const int mbase = blockIdx.x * MTILE;

    // ---- stage x -> xl (bf16, swizzled) ----
#pragma unroll
    for (int it = 0; it < 16; ++it) {
        int chunk = it * 256 + tid;                 // 8-float chunks, 32*128 total
        int row = chunk >> 7, col = (chunk & 127) * 8;
        const float* src = x + (size_t)(mbase + row) * 1024 + col;
        f32x4 v0 = *(const f32x4*)src;
        f32x4 v1 = *(const f32x4*)(src + 4);
        bf16x8 hv;
        hv[0] = (short)f2bf(v0[0]); hv[1] = (short)f2bf(v0[1]);
        hv[2] = (short)f2bf(v0[2]); hv[3] = (short)f2bf(v0[3]);
        hv[4] = (short)f2bf(v1[0]); hv[5] = (short)f2bf(v1[1]);
        hv[6] = (short)f2bf(v1[2]); hv[7] = (short)f2bf(v1[3]);
        int off = (row * 2048 + col * 2) ^ ((row & 7) << 4);
        *(bf16x8*)(xl + off) = hv;
    }
    __syncthreads();

    const f32x4 zf = {0.f, 0.f, 0.f, 0.f};

    for (int i = 0; i < 2; ++i) {
        // ---------- Phase A: GEMM1 (expert cols for this wave) + gate logits ----------
        f32x4 acc1[2][4] = {{zf, zf, zf, zf}, {zf, zf, zf, zf}};
        f32x4 accg[2] = {zf, zf};
        for (int kt = 0; kt < 32; ++kt) {
            bf16x8 a[2];
#pragma unroll
            for (int mt = 0; mt < 2; ++mt) {
                int row = mt * 16 + lc;
                int off = (row * 2048 + (kt * 32 + kg * 8) * 2) ^ ((row & 7) << 4);
                a[mt] = *(const bf16x8*)(xl + off);
            }
            const unsigned short* wb = w1f + (size_t)(i * 32 + kt) * 17 * 512;
#pragma unroll
            for (int nt = 0; nt < 4; ++nt) {
                bf16x8 b = *(const bf16x8*)(wb + (wid * 4 + nt) * 512 + lane * 8);
                acc1[0][nt] = MFMA_BF16(a[0], b, acc1[0][nt]);
                acc1[1][nt] = MFMA_BF16(a[1], b, acc1[1][nt]);
            }
            bf16x8 bg = *(const bf16x8*)(wb + 16 * 512 + lane * 8);
            accg[0] = MFMA_BF16(a[0], bg, accg[0]);
            accg[1] = MFMA_BF16(a[1], bg, accg[1]);
        }

        // ---------- gate softmax (logits live in lanes lc=0..3 of each 16-lane group) ----------
        float gate_val[2][4];
#pragma unroll
        for (int mt = 0; mt < 2; ++mt)
#pragma unroll
        for (int j = 0; j < 4; ++j) {
            int base = lane & 48;
            float l0 = __shfl(accg[mt][j], base + 0);
            float l1 = __shfl(accg[mt][j], base + 1);
            float l2 = __shfl(accg[mt][j], base + 2);
            float l3 = __shfl(accg[mt][j], base + 3);
            float m = fmaxf(fmaxf(l0, l1), fmaxf(l2, l3));
            float e0 = fast_exp(l0 - m), e1 = fast_exp(l1 - m);
            float e2 = fast_exp(l2 - m), e3 = fast_exp(l3 - m);
            float ge = wid == 0 ? e0 : wid == 1 ? e1 : wid == 2 ? e2 : e3;
            gate_val[mt][j] = ge * __builtin_amdgcn_rcpf(e0 + e1 + e2 + e3);
        }

        // ---------- v = tanh(Y) -> per-wave LDS slice [32][64] bf16 swizzled ----------
        char* vsl = sh + wid * 4096;
#pragma unroll
        for (int mt = 0; mt < 2; ++mt)
#pragma unroll
        for (int nt = 0; nt < 4; ++nt)
#pragma unroll
        for (int j = 0; j < 4; ++j) {
            int row = mt * 16 + kg * 4 + j;
            int q = nt * 16 + lc;
            int off = (row * 128 + q * 2) ^ ((row & 7) << 4);
            *(unsigned short*)(vsl + off) = f2bf(fast_tanh(acc1[mt][nt][j]));
        }

        // ---------- Phase B: c = v @ C[e]^T ----------
        f32x4 accc[2][4] = {{zf, zf, zf, zf}, {zf, zf, zf, zf}};
#pragma unroll
        for (int kt = 0; kt < 2; ++kt) {
            bf16x8 a[2];
#pragma unroll
            for (int mt = 0; mt < 2; ++mt) {
                int row = mt * 16 + lc;
                int off = (row * 128 + (kt * 32 + kg * 8) * 2) ^ ((row & 7) << 4);
                a[mt] = *(const bf16x8*)(vsl + off);
            }
            const unsigned short* cb = cf + (size_t)(((i * 4 + wid) * 2 + kt) * 4) * 512;
#pragma unroll
            for (int nt = 0; nt < 4; ++nt) {
                bf16x8 b = *(const bf16x8*)(cb + nt * 512 + lane * 8);
                accc[0][nt] = MFMA_BF16(a[0], b, accc[0][nt]);
                accc[1][nt] = MFMA_BF16(a[1], b, accc[1][nt]);
            }
        }
        __syncthreads();   // all v-slice reads done; re-purpose sh as gc

        // ---------- gc = gate * tanh(c) -> sh as [32][256] bf16 swizzled ----------
#pragma unroll
        for (int mt = 0; mt < 2; ++mt)
#pragma unroll
        for (int nt = 0; nt < 4; ++nt)
#pragma unroll
        for (int j = 0; j < 4; ++j) {
            int row = mt * 16 + kg * 4 + j;
            int colg = wid * 64 + nt * 16 + lc;
            float t = fast_tanh(accc[mt][nt][j]) * gate_val[mt][j];
            int off = (row * 512 + colg * 2) ^ ((row & 7) << 4);
            *(unsigned short*)(sh + off) = f2bf(t);
        }
        __syncthreads();

        // ---------- Phase C: Z = gc @ W2, fused epilogue ----------
        for (int half = 0; half < 2; ++half) {          // 128 d-cols per pass (VGPR relief)
            f32x4 acc2[2][8];
#pragma unroll
            for (int mt = 0; mt < 2; ++mt)
#pragma unroll
            for (int nt = 0; nt < 8; ++nt) acc2[mt][nt] = zf;

            for (int kt = 0; kt < 8; ++kt) {
                bf16x8 a[2];
#pragma unroll
                for (int mt = 0; mt < 2; ++mt) {
                    int row = mt * 16 + lc;
                    int off = (row * 512 + (kt * 32 + kg * 8) * 2) ^ ((row & 7) << 4);
                    a[mt] = *(const bf16x8*)(sh + off);
                }
                const unsigned short* w2b = w2f + (size_t)(i * 8 + kt) * 64 * 512;
#pragma unroll
                for (int nt = 0; nt < 8; ++nt) {
                    int ntg = wid * 16 + half * 8 + nt;
                    bf16x8 b = *(const bf16x8*)(w2b + ntg * 512 + lane * 8);
                    acc2[0][nt] = MFMA_BF16(a[0], b, acc2[0][nt]);
                    acc2[1][nt] = MFMA_BF16(a[1], b, acc2[1][nt]);
                }
            }
#pragma unroll
            for (int nt = 0; nt < 8; ++nt) {
                int d = wid * 256 + half * 128 + nt * 16 + lc;
                float bv = bias[(size_t)i * 1024 + d];
#pragma unroll
                for (int mt = 0; mt < 2; ++mt)
#pragma unroll
                for (int j = 0; j < 4; ++j) {
                    int row = mt * 16 + kg * 4 + j;
                    float z = acc2[mt][nt][j] + bv;
                    float x0v = x[(size_t)(mbase + row) * 1024 + d];
                    int xoff = (row * 2048 + d * 2) ^ ((row & 7) << 4);
                    float xlv = bf2f(*(const unsigned short*)(xl + xoff));
                    float o = x0v * z + xlv;                // x0*(Z+bias) + x_l
                    if (i == 0) {
                        *(unsigned short*)(xl + xoff) = f2bf(o);   // next layer's x_l
                    } else {
                        out[(size_t)(mbase + row) * 1024 + d] = o;
                    }
                }
            }
        }
        __syncthreads();   // xl rewritten / sh to be reused by next layer
    }
}

extern "C" void kernel_launch(void* const* d_in, const int* in_sizes, int n_in,
                              void* d_out, int out_size, void* d_ws, size_t ws_size,
                              hipStream_t stream) {
    const float* x     = (const float*)d_in[0];
    const float* U     = (const float*)d_in[1];
    const float* V     = (const float*)d_in[2];
    const float* C     = (const float*)d_in[3];
    const float* bias  = (const float*)d_in[4];
    const float* gateW = (const float*)d_in[5];
    unsigned short* ws = (unsigned short*)d_ws;
    float* out = (float*)d_out;

    const int prep_threads = 2 * 32 * 17 * 64 + 2 * 8 * 64 * 64 + 2 * 4 * 2 * 4 * 64; // 139264
    prep_weights<<<(prep_threads + 255) / 256, 256, 0, stream>>>(U, V, C, gateW, ws);
    dcn_main<<<kB / MTILE, 256, 0, stream>>>(x, bias, ws, out);
}

// Round 2
// 264.139 us; speedup vs baseline: 1.2766x; 1.2766x over previous
//
#include <hip/hip_runtime.h>
#include <stdint.h>

// DCN-V2 MoE low-rank cross network, fused both layers, bf16 MFMA.
// B=16384 D=1024 R=64 E=4 L=2.
//
// R1 -> R2: software-pipeline Phase A and Phase C K-loops (double-buffered
// A/B register prefetch, named even/odd buffers, full unroll). Theory: R1 was
// latency-bound (MfmaUtil 6.3%, VALUBusy 10.4%, HBM 8.6%, 8 waves/CU grid-cap)
// because each kt iteration serialized ~200cyc L2 B-loads against 50cyc of MFMA.
//
// Per layer (per 32-row block):
//   GEMM1: Y[32,272] = x_l[32,1024] @ W1  (W1 = [V cols e*64+r | gateW^T | pad])
//   gate  = softmax over 4 logit cols (every wave computes the gate N-tile)
//   v     = tanh(Y[:,0:256]);  per-wave expert slice in LDS
//   c     = tanh(v @ C[e]^T);  gc = gate_e * c   -> LDS [32][256] bf16
//   GEMM2: Z[32,1024] = gc @ W2  (W2[k=e*64+r][d] = U[e,d,r])
//   out   = x0 .* (Z + bias) + x_l    (residual; layer0 result re-staged as bf16 x_l)

typedef __attribute__((ext_vector_type(8))) short bf16x8;
typedef __attribute__((ext_vector_type(4))) float f32x4;

#define MFMA_BF16(a, b, c) __builtin_amdgcn_mfma_f32_16x16x32_bf16((a), (b), (c), 0, 0, 0)

static constexpr int kB = 16384, kD = 1024;
static constexpr int MTILE = 32;

// workspace layout in ushort elems
static constexpr size_t W1F_OFF = 0;                         // [L][32 kt][17 nt][64][8]
static constexpr size_t W1F_SZ  = 2ull * 32 * 17 * 64 * 8;   // 557056
static constexpr size_t W2F_OFF = W1F_OFF + W1F_SZ;          // [L][8 kt][64 nt][64][8]
static constexpr size_t W2F_SZ  = 2ull * 8 * 64 * 64 * 8;    // 524288
static constexpr size_t CF_OFF  = W2F_OFF + W2F_SZ;          // [L][E][2 kt][4 nt][64][8]

__device__ __forceinline__ unsigned short f2bf(float f) {
    uint32_t u = __builtin_bit_cast(uint32_t, f);
    u = (u + 0x7FFFu + ((u >> 16) & 1u)) >> 16;   // RNE
    return (unsigned short)u;
}
__device__ __forceinline__ float bf2f(unsigned short h) {
    uint32_t u = ((uint32_t)h) << 16;
    return __builtin_bit_cast(float, u);
}
__device__ __forceinline__ float fast_tanh(float x) {
    float e = __builtin_amdgcn_exp2f(x * 2.8853900817779268f);
    return 1.0f - 2.0f * __builtin_amdgcn_rcpf(e + 1.0f);
}
__device__ __forceinline__ float fast_exp(float x) {
    return __builtin_amdgcn_exp2f(x * 1.4426950408889634f);
}

// ---------------- weight prep: fp32 -> bf16 MFMA B-fragments ----------------
__global__ __launch_bounds__(256) void prep_weights(
    const float* __restrict__ U, const float* __restrict__ V,
    const float* __restrict__ C, const float* __restrict__ gateW,
    unsigned short* __restrict__ ws)
{
    const int id = blockIdx.x * 256 + threadIdx.x;
    const int lane = id & 63;
    const int kg = lane >> 4, c = lane & 15;
    if (id < 2 * 32 * 17 * 64) {                       // W1 fragments
        int t = id >> 6;
        int nt = t % 17; t /= 17;
        int kt = t & 31; int i = t >> 5;
        int col = nt * 16 + c;
        bf16x8 o;
#pragma unroll
        for (int j = 0; j < 8; ++j) {
            int k = kt * 32 + kg * 8 + j;              // k = d
            float v = 0.0f;
            if (col < 256) {
                int e = col >> 6, r = col & 63;
                v = V[((size_t)(i * 4 + e) * 1024 + k) * 64 + r];
            } else if (col < 260) {
                v = gateW[(size_t)(col - 256) * 1024 + k];
            }
            o[j] = (short)f2bf(v);
        }
        *(bf16x8*)(ws + W1F_OFF + (size_t)id * 8) = o;
    } else if (id < 2 * 32 * 17 * 64 + 2 * 8 * 64 * 64) {  // W2 fragments
        int id2 = id - 2 * 32 * 17 * 64;
        int t = id2 >> 6;
        int nt = t & 63; t >>= 6;
        int kt = t & 7;  int i = t >> 3;
        int d = nt * 16 + c;
        bf16x8 o;
#pragma unroll
        for (int j = 0; j < 8; ++j) {
            int k = kt * 32 + kg * 8 + j;              // k = e*64 + r
            int e = k >> 6, r = k & 63;
            o[j] = (short)f2bf(U[((size_t)(i * 4 + e) * 1024 + d) * 64 + r]);
        }
        *(bf16x8*)(ws + W2F_OFF + (size_t)id2 * 8) = o;
    } else if (id < 2 * 32 * 17 * 64 + 2 * 8 * 64 * 64 + 2 * 4 * 2 * 4 * 64) {  // C frags
        int id3 = id - (2 * 32 * 17 * 64 + 2 * 8 * 64 * 64);
        int t = id3 >> 6;
        int nt = t & 3; t >>= 2;
        int kt = t & 1; t >>= 1;
        int e = t & 3;  int i = t >> 2;
        int r = nt * 16 + c;
        bf16x8 o;
#pragma unroll
        for (int j = 0; j < 8; ++j) {
            int q = kt * 32 + kg * 8 + j;
            o[j] = (short)f2bf(C[((size_t)(i * 4 + e) * 64 + r) * 64 + q]);
        }
        *(bf16x8*)(ws + CF_OFF + (size_t)id3 * 8) = o;
    }
}

// ---------------- fused main kernel ----------------
__global__ __launch_bounds__(256, 2) void dcn_main(
    const float* __restrict__ x, const float* __restrict__ bias,
    const unsigned short* __restrict__ ws, float* __restrict__ out)
{
    __shared__ char smem[64 * 1024 + 16 * 1024];   // 80 KiB -> 2 blocks/CU (grid-capped anyway)
    char* xl = smem;                    // x_l tile [32][1024] bf16, XOR-swizzled
    char* sh = smem + 64 * 1024;        // 16 KiB: v slices (4KB/wave), then gc [32][256]

    const unsigned short* w1f = ws + W1F_OFF;
    const unsigned short* w2f = ws + W2F_OFF;
    const unsigned short* cf  = ws + CF_OFF;

    const int tid = threadIdx.x;
    const int lane = tid & 63, wid = tid >> 6;
    const int kg = lane >> 4, lc = lane & 15;
    const int mbase = blockIdx.x * MTILE;

    // ---- stage x -> xl (bf16, swizzled); loads independent -> pipelined ----
#pragma unroll
    for (int it = 0; it < 16; ++it) {
        int chunk = it * 256 + tid;                 // 8-float chunks, 32*128 total
        int row = chunk >> 7, col = (chunk & 127) * 8;
        const float* src = x + (size_t)(mbase + row) * 1024 + col;
        f32x4 v0 = *(const f32x4*)src;
        f32x4 v1 = *(const f32x4*)(src + 4);
        bf16x8 hv;
        hv[0] = (short)f2bf(v0[0]); hv[1] = (short)f2bf(v0[1]);
        hv[2] = (short)f2bf(v0[2]); hv[3] = (short)f2bf(v0[3]);
        hv[4] = (short)f2bf(v1[0]); hv[5] = (short)f2bf(v1[1]);
        hv[6] = (short)f2bf(v1[2]); hv[7] = (short)f2bf(v1[3]);
        int off = (row * 2048 + col * 2) ^ ((row & 7) << 4);
        *(bf16x8*)(xl + off) = hv;
    }
    __syncthreads();

    const f32x4 zf = {0.f, 0.f, 0.f, 0.f};

    for (int i = 0; i < 2; ++i) {
        // ---------- Phase A: GEMM1 (expert cols for this wave) + gate logits ----------
        // software-pipelined: named even/odd A/B register buffers (rule #20: static idx)
        f32x4 acc1[2][4] = {{zf, zf, zf, zf}, {zf, zf, zf, zf}};
        f32x4 accg[2] = {zf, zf};
        {
            auto ldA = [&](bf16x8* a, int kt) {
#pragma unroll
                for (int mt = 0; mt < 2; ++mt) {
                    int row = mt * 16 + lc;
                    int off = (row * 2048 + (kt * 32 + kg * 8) * 2) ^ ((row & 7) << 4);
                    a[mt] = *(const bf16x8*)(xl + off);
                }
            };
            auto ldB = [&](bf16x8* b, int kt) {
                const unsigned short* wb = w1f + (size_t)(i * 32 + kt) * 17 * 512;
#pragma unroll
                for (int nt = 0; nt < 4; ++nt)
                    b[nt] = *(const bf16x8*)(wb + (wid * 4 + nt) * 512 + lane * 8);
                b[4] = *(const bf16x8*)(wb + 16 * 512 + lane * 8);
            };
            auto fm = [&](const bf16x8* a, const bf16x8* b) {
#pragma unroll
                for (int nt = 0; nt < 4; ++nt) {
                    acc1[0][nt] = MFMA_BF16(a[0], b[nt], acc1[0][nt]);
                    acc1[1][nt] = MFMA_BF16(a[1], b[nt], acc1[1][nt]);
                }
                accg[0] = MFMA_BF16(a[0], b[4], accg[0]);
                accg[1] = MFMA_BF16(a[1], b[4], accg[1]);
            };
            bf16x8 aA[2], aB[2], bA[5], bB[5];
            ldA(aA, 0); ldB(bA, 0);
#pragma unroll
            for (int k2 = 0; k2 < 16; ++k2) {
                ldA(aB, 2 * k2 + 1); ldB(bB, 2 * k2 + 1);
                fm(aA, bA);
                if (k2 < 15) { ldA(aA, 2 * k2 + 2); ldB(bA, 2 * k2 + 2); }
                fm(aB, bB);
            }
        }

        // ---------- v = tanh(Y) -> per-wave LDS slice [32][64] bf16 swizzled ----------
        char* vsl = sh + wid * 4096;
#pragma unroll
        for (int mt = 0; mt < 2; ++mt)
#pragma unroll
        for (int nt = 0; nt < 4; ++nt)
#pragma unroll
        for (int j = 0; j < 4; ++j) {
            int row = mt * 16 + kg * 4 + j;
            int q = nt * 16 + lc;
            int off = (row * 128 + q * 2) ^ ((row & 7) << 4);
            *(unsigned short*)(vsl + off) = f2bf(fast_tanh(acc1[mt][nt][j]));
        }

        // ---------- gate softmax (overlaps LDS writes above) ----------
        float gate_val[2][4];
#pragma unroll
        for (int mt = 0; mt < 2; ++mt)
#pragma unroll
        for (int j = 0; j < 4; ++j) {
            int base = lane & 48;
            float l0 = __shfl(accg[mt][j], base + 0);
            float l1 = __shfl(accg[mt][j], base + 1);
            float l2 = __shfl(accg[mt][j], base + 2);
            float l3 = __shfl(accg[mt][j], base + 3);
            float m = fmaxf(fmaxf(l0, l1), fmaxf(l2, l3));
            float e0 = fast_exp(l0 - m), e1 = fast_exp(l1 - m);
            float e2 = fast_exp(l2 - m), e3 = fast_exp(l3 - m);
            float ge = wid == 0 ? e0 : wid == 1 ? e1 : wid == 2 ? e2 : e3;
            gate_val[mt][j] = ge * __builtin_amdgcn_rcpf(e0 + e1 + e2 + e3);
        }

        // ---------- Phase B: c = v @ C[e]^T (tiny; straight-line, loads up front) ----------
        f32x4 accc[2][4] = {{zf, zf, zf, zf}, {zf, zf, zf, zf}};
        {
            bf16x8 a0[2], a1[2], cb0[4], cb1[4];
            const unsigned short* cb = cf + (size_t)(((i * 4 + wid) * 2 + 0) * 4) * 512;
            const unsigned short* cb_1 = cf + (size_t)(((i * 4 + wid) * 2 + 1) * 4) * 512;
#pragma unroll
            for (int nt = 0; nt < 4; ++nt) {
                cb0[nt] = *(const bf16x8*)(cb + nt * 512 + lane * 8);
                cb1[nt] = *(const bf16x8*)(cb_1 + nt * 512 + lane * 8);
            }
#pragma unroll
            for (int mt = 0; mt < 2; ++mt) {
                int row = mt * 16 + lc;
                int off0 = (row * 128 + (0 * 32 + kg * 8) * 2) ^ ((row & 7) << 4);
                int off1 = (row * 128 + (1 * 32 + kg * 8) * 2) ^ ((row & 7) << 4);
                a0[mt] = *(const bf16x8*)(vsl + off0);
                a1[mt] = *(const bf16x8*)(vsl + off1);
            }
#pragma unroll
            for (int nt = 0; nt < 4; ++nt) {
                accc[0][nt] = MFMA_BF16(a0[0], cb0[nt], accc[0][nt]);
                accc[1][nt] = MFMA_BF16(a0[1], cb0[nt], accc[1][nt]);
                accc[0][nt] = MFMA_BF16(a1[0], cb1[nt], accc[0][nt]);
                accc[1][nt] = MFMA_BF16(a1[1], cb1[nt], accc[1][nt]);
            }
        }
        __syncthreads();   // all v-slice reads done; re-purpose sh as gc

        // ---------- gc = gate * tanh(c) -> sh as [32][256] bf16 swizzled ----------
#pragma unroll
        for (int mt = 0; mt < 2; ++mt)
#pragma unroll
        for (int nt = 0; nt < 4; ++nt)
#pragma unroll
        for (int j = 0; j < 4; ++j) {
            int row = mt * 16 + kg * 4 + j;
            int colg = wid * 64 + nt * 16 + lc;
            float t = fast_tanh(accc[mt][nt][j]) * gate_val[mt][j];
            int off = (row * 512 + colg * 2) ^ ((row & 7) << 4);
            *(unsigned short*)(sh + off) = f2bf(t);
        }
        __syncthreads();

        // ---------- Phase C: Z = gc @ W2, pipelined; fused epilogue ----------
        for (int half = 0; half < 2; ++half) {          // 128 d-cols per pass
            f32x4 acc2[2][8];
#pragma unroll
            for (int mt = 0; mt < 2; ++mt)
#pragma unroll
            for (int nt = 0; nt < 8; ++nt) acc2[mt][nt] = zf;

            auto ldA2 = [&](bf16x8* a, int kt) {
#pragma unroll
                for (int mt = 0; mt < 2; ++mt) {
                    int row = mt * 16 + lc;
                    int off = (row * 512 + (kt * 32 + kg * 8) * 2) ^ ((row & 7) << 4);
                    a[mt] = *(const bf16x8*)(sh + off);
                }
            };
            auto ldB2 = [&](bf16x8* b, int kt) {
                const unsigned short* w2b = w2f + (size_t)(i * 8 + kt) * 64 * 512;
#pragma unroll
                for (int nt = 0; nt < 8; ++nt)
                    b[nt] = *(const bf16x8*)(w2b + (wid * 16 + half * 8 + nt) * 512 + lane * 8);
            };
            auto fm2 = [&](const bf16x8* a, const bf16x8* b) {
#pragma unroll
                for (int nt = 0; nt < 8; ++nt) {
                    acc2[0][nt] = MFMA_BF16(a[0], b[nt], acc2[0][nt]);
                    acc2[1][nt] = MFMA_BF16(a[1], b[nt], acc2[1][nt]);
                }
            };
            bf16x8 aA[2], aB[2], bA[8], bB[8];
            ldA2(aA, 0); ldB2(bA, 0);
#pragma unroll
            for (int k2 = 0; k2 < 4; ++k2) {
                ldA2(aB, 2 * k2 + 1); ldB2(bB, 2 * k2 + 1);
                fm2(aA, bA);
                if (k2 < 3) { ldA2(aA, 2 * k2 + 2); ldB2(bA, 2 * k2 + 2); }
                fm2(aB, bB);
            }

#pragma unroll
            for (int nt = 0; nt < 8; ++nt) {
                int d = wid * 256 + half * 128 + nt * 16 + lc;
                float bv = bias[(size_t)i * 1024 + d];
#pragma unroll
                for (int mt = 0; mt < 2; ++mt)
#pragma unroll
                for (int j = 0; j < 4; ++j) {
                    int row = mt * 16 + kg * 4 + j;
                    float z = acc2[mt][nt][j] + bv;
                    float x0v = x[(size_t)(mbase + row) * 1024 + d];
                    int xoff = (row * 2048 + d * 2) ^ ((row & 7) << 4);
                    float xlv = bf2f(*(const unsigned short*)(xl + xoff));
                    float o = x0v * z + xlv;                // x0*(Z+bias) + x_l
                    if (i == 0) {
                        *(unsigned short*)(xl + xoff) = f2bf(o);   // next layer's x_l
                    } else {
                        out[(size_t)(mbase + row) * 1024 + d] = o;
                    }
                }
            }
        }
        __syncthreads();   // xl rewritten / sh to be reused by next layer
    }
}

extern "C" void kernel_launch(void* const* d_in, const int* in_sizes, int n_in,
                              void* d_out, int out_size, void* d_ws, size_t ws_size,
                              hipStream_t stream) {
    const float* x     = (const float*)d_in[0];
    const float* U     = (const float*)d_in[1];
    const float* V     = (const float*)d_in[2];
    const float* C     = (const float*)d_in[3];
    const float* bias  = (const float*)d_in[4];
    const float* gateW = (const float*)d_in[5];
    unsigned short* ws = (unsigned short*)d_ws;
    float* out = (float*)d_out;

    const int prep_threads = 2 * 32 * 17 * 64 + 2 * 8 * 64 * 64 + 2 * 4 * 2 * 4 * 64; // 139264
    prep_weights<<<(prep_threads + 255) / 256, 256, 0, stream>>>(U, V, C, gateW, ws);
    dcn_main<<<kB / MTILE, 256, 0, stream>>>(x, bias, ws, out);
}